// Round 13
// baseline (126.534 us; speedup 1.0000x reference)
//
#include <hip/hip_runtime.h>
#include <hip/hip_fp16.h>
#include <math.h>

#define EPSF 1e-7f
#define MIN_NORM 1e-15f
#define MAXNORM 0.996f   // (1 - 0.004)/sqrt(c), c=1
#define NEG_SLOPE 0.2f

typedef __attribute__((ext_vector_type(8))) short short8;
typedef __attribute__((ext_vector_type(4))) float f32x4;

__device__ __forceinline__ float wave_reduce_sum(float v) {
    #pragma unroll
    for (int m = 1; m < 64; m <<= 1) v += __shfl_xor(v, m, 64);
    return v;
}

// fast tanh via HW exp: t = 1 - 2/(e^{2x}+1). Safe for x>=0 (saturates to 1).
__device__ __forceinline__ float fast_tanh(float x) {
    float e = __expf(2.f * x);
    return 1.f - 2.f / (e + 1.f);
}

// fast artanh via HW log: 0.5*ln((1+x)/(1-x)), input clamped like reference
__device__ __forceinline__ float fast_artanh(float x) {
    x = fminf(fmaxf(x, -1.f + EPSF), 1.f - EPSF);
    return 0.5f * __logf((1.f + x) / (1.f - x));
}

__device__ __forceinline__ float lrelu(float a) {
    return a < 0.f ? a * NEG_SLOPE : a;
}

// bf16 round-to-nearest-even (no NaN handling; inputs are tame)
__device__ __forceinline__ unsigned short f2bf(float f) {
    unsigned u = __float_as_uint(f);
    u += 0x7FFFu + ((u >> 16) & 1u);
    return (unsigned short)(u >> 16);
}
__device__ __forceinline__ float bf2f(unsigned short h) {
    return __uint_as_float(((unsigned)h) << 16);
}

__device__ __forceinline__ unsigned byteof(unsigned x, int k) {
    return (x >> (8 * k)) & 0xffu;
}

// ---- K0: prep = wsplit (blocks 0..63) + hyp bias (block 64) + head init (65..)
__global__ void prep_kernel(const float* __restrict__ W,
                            unsigned short* __restrict__ whi,
                            unsigned short* __restrict__ wlo,
                            const float* __restrict__ lin_bias,
                            float* __restrict__ bbuf,
                            int* __restrict__ head, int headN) {
    if (blockIdx.x >= 65) {
        int i = (blockIdx.x - 65) * 1024 + threadIdx.x * 4;
        if (i < headN) *(int4*)&head[i] = make_int4(-1, -1, -1, -1);
        return;
    }
    if (blockIdx.x == 64) {
        if (threadIdx.x >= 64) return;
        int lane = threadIdx.x;
        float u0 = lin_bias[lane], u1 = lin_bias[lane + 64];
        float n2 = wave_reduce_sum(u0 * u0 + u1 * u1);
        float n = fmaxf(sqrtf(n2), MIN_NORM);
        float s = tanhf(n) / n;
        float b0 = s * u0, b1 = s * u1;
        float bn = fmaxf(tanhf(n), MIN_NORM);
        float fn2 = bn * bn;
        if (bn > MAXNORM) { float f = MAXNORM / bn; b0 *= f; b1 *= f; fn2 = MAXNORM * MAXNORM; }
        bbuf[lane] = b0;
        bbuf[lane + 64] = b1;
        if (lane == 0) bbuf[128] = fn2;
        return;
    }
    int idx = blockIdx.x * 256 + threadIdx.x;   // 0..16383
    int i = idx & 7, l = (idx >> 3) & 63, ts = idx >> 9;
    int s = ts & 3, t = ts >> 2;
    int o = t * 16 + (l & 15);
    int k = s * 32 + ((l >> 4) * 8) + i;
    float f = W[o * 128 + k];
    unsigned short h = f2bf(f);
    unsigned short lo = f2bf(f - bf2f(h));
    whi[idx] = h;
    wlo[idx] = lo;
}

// ---- K1: per-node transform, MFMA matvec (bf16x3) + 16-lane-per-node chain.
// Messages stored int8 row-quantized: row = 64 ushorts, ushort d = (q_d, q_{d+64});
// scl[n] = rowmax/127. s_i/s_j in permuted head order [h0,h2,h1,h3].
#define DPAD 132
__global__ __launch_bounds__(256) void node_kernel(
    const float* __restrict__ x,
    const unsigned short* __restrict__ whi, const unsigned short* __restrict__ wlo,
    const float* __restrict__ bbuf, const float* __restrict__ att,
    unsigned short* __restrict__ logq, float* __restrict__ scl,
    float* __restrict__ s_i, float* __restrict__ s_j, int N)
{
    __shared__ float mxs[16][DPAD];
    __shared__ float xn2s[16];
    int tid = threadIdx.x, wave = tid >> 6, lane = tid & 63;
    int nbase = blockIdx.x * 16;
    int arow = lane & 15, kgrp = lane >> 4;
    int anode = min(nbase + arow, N - 1);

    f32x4 acc0 = {0.f, 0.f, 0.f, 0.f};
    f32x4 acc1 = {0.f, 0.f, 0.f, 0.f};
    int t0 = wave * 2, t1 = wave * 2 + 1;
    float x2loc = 0.f;

    #pragma unroll
    for (int s = 0; s < 4; ++s) {
        const float* xp = x + (size_t)anode * 128 + s * 32 + kgrp * 8;
        float4 xa = *(const float4*)xp;
        float4 xb = *(const float4*)(xp + 4);
        float xv[8] = {xa.x, xa.y, xa.z, xa.w, xb.x, xb.y, xb.z, xb.w};
        short8 ahi, alo;
        #pragma unroll
        for (int i = 0; i < 8; ++i) {
            unsigned short h = f2bf(xv[i]);
            unsigned short l = f2bf(xv[i] - bf2f(h));
            ahi[i] = (short)h;
            alo[i] = (short)l;
        }
        if (wave == 0) {
            #pragma unroll
            for (int i = 0; i < 8; ++i) x2loc = fmaf(xv[i], xv[i], x2loc);
        }
        short8 bh0 = *(const short8*)(whi + ((size_t)(t0 * 4 + s) * 64 + lane) * 8);
        short8 bl0 = *(const short8*)(wlo + ((size_t)(t0 * 4 + s) * 64 + lane) * 8);
        short8 bh1 = *(const short8*)(whi + ((size_t)(t1 * 4 + s) * 64 + lane) * 8);
        short8 bl1 = *(const short8*)(wlo + ((size_t)(t1 * 4 + s) * 64 + lane) * 8);
        acc0 = __builtin_amdgcn_mfma_f32_16x16x32_bf16(ahi, bh0, acc0, 0, 0, 0);
        acc0 = __builtin_amdgcn_mfma_f32_16x16x32_bf16(alo, bh0, acc0, 0, 0, 0);
        acc0 = __builtin_amdgcn_mfma_f32_16x16x32_bf16(ahi, bl0, acc0, 0, 0, 0);
        acc1 = __builtin_amdgcn_mfma_f32_16x16x32_bf16(ahi, bh1, acc1, 0, 0, 0);
        acc1 = __builtin_amdgcn_mfma_f32_16x16x32_bf16(alo, bh1, acc1, 0, 0, 0);
        acc1 = __builtin_amdgcn_mfma_f32_16x16x32_bf16(ahi, bl1, acc1, 0, 0, 0);
    }
    if (wave == 0) {
        x2loc += __shfl_xor(x2loc, 16, 64);
        x2loc += __shfl_xor(x2loc, 32, 64);
        if (lane < 16) xn2s[lane] = x2loc;
    }
    #pragma unroll
    for (int r = 0; r < 4; ++r) {
        mxs[kgrp * 4 + r][t0 * 16 + arow] = acc0[r];
        mxs[kgrp * 4 + r][t1 * 16 + arow] = acc1[r];
    }
    __syncthreads();

    // ---- chain: 16 lanes per node, 8 dims per lane, 4 nodes per wave ----
    int g16 = lane >> 4, l16 = lane & 15;
    int nn = wave * 4 + g16;
    int node = nbase + nn;
    bool valid = node < N;
    int head = l16 >> 2;
    int dbase = l16 * 8;
    int dd8 = (l16 & 3) * 8;
    float bb[8], aiv[8], ajv[8];
    #pragma unroll
    for (int j = 0; j < 8; ++j) {
        bb[j] = bbuf[dbase + j];
        aiv[j] = att[head * 64 + dd8 + j];
        ajv[j] = att[head * 64 + 32 + dd8 + j];
    }
    float y2 = bbuf[128];

    float4 va = *(const float4*)&mxs[nn][dbase];
    float4 vb = *(const float4*)&mxs[nn][dbase + 4];
    float v[8] = {va.x, va.y, va.z, va.w, vb.x, vb.y, vb.z, vb.w};

    float mq = 0.f;
    #pragma unroll
    for (int j = 0; j < 8; ++j) mq = fmaf(v[j], v[j], mq);
    #pragma unroll
    for (int m = 1; m < 16; m <<= 1) mq += __shfl_xor(mq, m, 64);

    float xn2 = xn2s[nn];
    float xn = fmaxf(sqrtf(xn2), MIN_NORM);
    float mxn = fmaxf(sqrtf(mq), MIN_NORM);
    float t = fast_tanh(mxn / xn * fast_artanh(xn));
    float scl_ = t / mxn;
    bool zero = (mq == 0.f);
    float r[8];
    #pragma unroll
    for (int j = 0; j < 8; ++j) r[j] = zero ? 0.f : scl_ * v[j];
    float rn2 = zero ? 0.f : t * t;
    float rn = zero ? MIN_NORM : fmaxf(fabsf(t), MIN_NORM);
    float x2 = rn2;
    if (rn > MAXNORM) {
        float f = MAXNORM / rn;
        #pragma unroll
        for (int j = 0; j < 8; ++j) r[j] *= f;
        x2 = MAXNORM * MAXNORM;
    }
    float xy = 0.f;
    #pragma unroll
    for (int j = 0; j < 8; ++j) xy = fmaf(r[j], bb[j], xy);
    #pragma unroll
    for (int m = 1; m < 16; m <<= 1) xy += __shfl_xor(xy, m, 64);
    float cA = 1.f + 2.f * xy + y2;
    float cB = 1.f - x2;
    float dn = fmaxf(1.f + 2.f * xy + x2 * y2, MIN_NORM);
    float inv = 1.f / dn;
    float h[8];
    #pragma unroll
    for (int j = 0; j < 8; ++j) h[j] = (cA * r[j] + cB * bb[j]) * inv;
    float hq = 0.f;
    #pragma unroll
    for (int j = 0; j < 8; ++j) hq = fmaf(h[j], h[j], hq);
    #pragma unroll
    for (int m = 1; m < 16; m <<= 1) hq += __shfl_xor(hq, m, 64);
    float hn = fmaxf(sqrtf(hq), MIN_NORM);
    float ln2 = hq;
    if (hn > MAXNORM) {
        float f = MAXNORM / hn;
        #pragma unroll
        for (int j = 0; j < 8; ++j) h[j] *= f;
        ln2 = MAXNORM * MAXNORM;
    }
    float lnn = fmaxf(sqrtf(ln2), MIN_NORM);
    float ls = fast_artanh(lnn) / lnn;
    float lv[8];
    #pragma unroll
    for (int j = 0; j < 8; ++j) lv[j] = ls * h[j];

    // ---- int8 row quantization: s = max|lv| over the node's 16 lanes ----
    float rm = 0.f;
    #pragma unroll
    for (int j = 0; j < 8; ++j) rm = fmaxf(rm, fabsf(lv[j]));
    #pragma unroll
    for (int m = 1; m < 16; m <<= 1) rm = fmaxf(rm, __shfl_xor(rm, m, 64));
    float s127 = rm * (1.f / 127.f);
    float qs = rm > 0.f ? 127.f / rm : 0.f;
    int q[8];
    #pragma unroll
    for (int j = 0; j < 8; ++j) q[j] = (int)rintf(lv[j] * qs);
    unsigned o0 = (q[0] & 255) | ((q[1] & 255) << 8) | ((q[2] & 255) << 16) | ((unsigned)(q[3] & 255) << 24);
    unsigned o1 = (q[4] & 255) | ((q[5] & 255) << 8) | ((q[6] & 255) << 16) | ((unsigned)(q[7] & 255) << 24);
    unsigned p0 = __shfl_xor(o0, 8, 64);
    unsigned p1 = __shfl_xor(o1, 8, 64);
    if (valid && l16 < 8) {
        uint4 pk;
        pk.x = byteof(o0,0) | (byteof(p0,0) << 8) | (byteof(o0,1) << 16) | (byteof(p0,1) << 24);
        pk.y = byteof(o0,2) | (byteof(p0,2) << 8) | (byteof(o0,3) << 16) | (byteof(p0,3) << 24);
        pk.z = byteof(o1,0) | (byteof(p1,0) << 8) | (byteof(o1,1) << 16) | (byteof(p1,1) << 24);
        pk.w = byteof(o1,2) | (byteof(p1,2) << 8) | (byteof(o1,3) << 16) | (byteof(p1,3) << 24);
        *(uint4*)((char*)logq + ((size_t)node << 7) + l16 * 16) = pk;
    }
    if (valid && l16 == 0) scl[node] = s127;

    float pi = 0.f, pj = 0.f;
    #pragma unroll
    for (int j = 0; j < 8; ++j) {
        pi = fmaf(lv[j], aiv[j], pi);
        pj = fmaf(lv[j], ajv[j], pj);
    }
    pi += __shfl_xor(pi, 1, 64); pi += __shfl_xor(pi, 2, 64);
    pj += __shfl_xor(pj, 1, 64); pj += __shfl_xor(pj, 2, 64);
    if (valid && (l16 & 3) == 0) {
        int pos = ((head & 1) << 1) | (head >> 1);   // [h0,h2,h1,h3] order
        s_i[(size_t)node * 4 + pos] = pi;
        s_j[(size_t)node * 4 + pos] = pj;
    }
}

// ---- K2: fused list-build + streaming weight precompute + src scale stream.
// pair16[e] = { src_byte_offset, next, half2(w_h0,w_h2), half2(w_h1,w_h3) }
// sacc[e]   = scl[src[e]]  (indexed by e -> loads in parallel with pair16 in walk)
__global__ void buildw_kernel(const int* __restrict__ src, const int* __restrict__ dst,
                              int E, const float* __restrict__ s_i,
                              const float* __restrict__ s_j, const float* __restrict__ scl,
                              int* __restrict__ head, int4* __restrict__ pair16,
                              float* __restrict__ sacc)
{
    int e = blockIdx.x * blockDim.x + threadIdx.x;
    if (e >= E) return;
    int s_ = src[e], d_ = dst[e];
    int prev = atomicExch(&head[(size_t)d_ * 16 + (e & 15)], e);
    float4 si = *(const float4*)(s_i + (size_t)d_ * 4);
    float4 sj = *(const float4*)(s_j + (size_t)s_ * 4);
    float sa = scl[s_];
    float w0 = __expf(lrelu(si.x + sj.x));
    float w1 = __expf(lrelu(si.y + sj.y));
    float w2 = __expf(lrelu(si.z + sj.z));
    float w3 = __expf(lrelu(si.w + sj.w));
    __half2 h01 = __floats2half2_rn(w0, w1);   // (h0, h2) in permuted order
    __half2 h23 = __floats2half2_rn(w2, w3);   // (h1, h3)
    int4 pr;
    pr.x = s_ << 7;        // byte offset of int8 message row (128 B/row)
    pr.y = prev;
    pr.z = *(int*)&h01;
    pr.w = *(int*)&h23;
    pair16[e] = pr;
    sacc[e] = sa;
}

// ---- K3: aggregate. Walk 16 chains (pair16[e] || sacc[e] parallel loads,
// wacc = wden*s127 via 2 pk-muls) -> LDS {off, wden, wacc}; hot loop per edge:
// ONE ushort gather + sext unpack + 2 fma + 2 add.
#define MAXS 128
__global__ __launch_bounds__(256) void aggregate_kernel(
    const int* __restrict__ head, const int4* __restrict__ pair16,
    const float* __restrict__ sacc,
    const float* __restrict__ s_i, const float* __restrict__ s_j,
    const float* __restrict__ scl,
    const unsigned short* __restrict__ logq, const float* __restrict__ conv_bias,
    float* __restrict__ out, int N)
{
    __shared__ __align__(16) int slist[4][MAXS];
    __shared__ __align__(16) unsigned wlist[4][MAXS * 4];
    __shared__ int scnt[4];
    int tid = threadIdx.x, wave = tid >> 6, lane = tid & 63;
    int n = blockIdx.x * 4 + wave;
    bool valid = n < N;

    if (lane == 0) scnt[wave] = 0;
    __syncthreads();

    int resume = -1;
    if (valid && lane < 16) {
        int e = head[(size_t)n * 16 + lane];
        while (e >= 0) {
            int4 pr = pair16[e];
            float sa = sacc[e];                 // parallel load, same index
            int pos = atomicAdd(&scnt[wave], 1);
            if (pos < MAXS) {
                float2 f01 = __half22float2(*(const __half2*)&pr.z);
                float2 f23 = __half22float2(*(const __half2*)&pr.w);
                __half2 a01 = __floats2half2_rn(f01.x * sa, f01.y * sa);
                __half2 a23 = __floats2half2_rn(f23.x * sa, f23.y * sa);
                slist[wave][pos] = pr.x;
                wlist[wave][pos * 4 + 0] = (unsigned)pr.z;
                wlist[wave][pos * 4 + 1] = (unsigned)pr.w;
                wlist[wave][pos * 4 + 2] = *(unsigned*)&a01;
                wlist[wave][pos * 4 + 3] = *(unsigned*)&a23;
                e = pr.y;
            } else { resume = e; break; }
        }
    }
    __syncthreads();

    int g = lane >> 5;
    float acc0 = 0.f, acc1 = 0.f, dna = 0.f, dnb = 0.f;
    float sia = 0.f, sib = 0.f;

    int deg = 0;
    if (valid) {
        deg = min(scnt[wave], MAXS);
        float2 si2  = *(const float2*)(s_i + (size_t)n * 4 + g * 2);
        float2 sj2n = *(const float2*)(s_j + (size_t)n * 4 + g * 2);
        sia = si2.x; sib = si2.y;
        float ea = __expf(lrelu(sia + sj2n.x));
        float eb = __expf(lrelu(sib + sj2n.y));
        dna = ea; dnb = eb;
        float sn = scl[n];
        unsigned short us = *(const unsigned short*)((const char*)logq + ((size_t)n << 7) + lane * 2);
        int q0s = (signed char)(us & 0xff);
        int q1s = (signed char)(us >> 8);
        acc0 = (ea * sn) * (float)q0s;
        acc1 = (eb * sn) * (float)q1s;

        const int* sl = slist[wave];
        const unsigned* wlv = wlist[wave];
        int i = 0;
        for (; i + 8 <= deg; i += 8) {
            int4 offqa = *(const int4*)&sl[i];
            int4 offqb = *(const int4*)&sl[i + 4];
            int offs[8] = {offqa.x, offqa.y, offqa.z, offqa.w,
                           offqb.x, offqb.y, offqb.z, offqb.w};
            unsigned wd[8], wa[8];
            unsigned short uu[8];
            #pragma unroll
            for (int j = 0; j < 8; ++j) {
                wd[j] = wlv[(i + j) * 4 + g];
                wa[j] = wlv[(i + j) * 4 + 2 + g];
                uu[j] = *(const unsigned short*)((const char*)logq + offs[j] + lane * 2);
            }
            #pragma unroll
            for (int j = 0; j < 8; ++j) {
                float2 wf = __half22float2(*(const __half2*)&wd[j]);
                float2 af = __half22float2(*(const __half2*)&wa[j]);
                int q0 = (signed char)(uu[j] & 0xff);
                int q1 = (signed char)(uu[j] >> 8);
                dna += wf.x; dnb += wf.y;
                acc0 = fmaf(af.x, (float)q0, acc0);
                acc1 = fmaf(af.y, (float)q1, acc1);
            }
        }
        for (; i + 4 <= deg; i += 4) {
            int4 offq = *(const int4*)&sl[i];
            int offs[4] = {offq.x, offq.y, offq.z, offq.w};
            unsigned wd[4], wa[4];
            unsigned short uu[4];
            #pragma unroll
            for (int j = 0; j < 4; ++j) {
                wd[j] = wlv[(i + j) * 4 + g];
                wa[j] = wlv[(i + j) * 4 + 2 + g];
                uu[j] = *(const unsigned short*)((const char*)logq + offs[j] + lane * 2);
            }
            #pragma unroll
            for (int j = 0; j < 4; ++j) {
                float2 wf = __half22float2(*(const __half2*)&wd[j]);
                float2 af = __half22float2(*(const __half2*)&wa[j]);
                int q0 = (signed char)(uu[j] & 0xff);
                int q1 = (signed char)(uu[j] >> 8);
                dna += wf.x; dnb += wf.y;
                acc0 = fmaf(af.x, (float)q0, acc0);
                acc1 = fmaf(af.y, (float)q1, acc1);
            }
        }
        for (; i < deg; ++i) {
            unsigned wd = wlv[i * 4 + g];
            unsigned wa = wlv[i * 4 + 2 + g];
            unsigned short uu = *(const unsigned short*)((const char*)logq + sl[i] + lane * 2);
            float2 wf = __half22float2(*(const __half2*)&wd);
            float2 af = __half22float2(*(const __half2*)&wa);
            int q0 = (signed char)(uu & 0xff);
            int q1 = (signed char)(uu >> 8);
            dna += wf.x; dnb += wf.y;
            acc0 = fmaf(af.x, (float)q0, acc0);
            acc1 = fmaf(af.y, (float)q1, acc1);
        }
    }

    // cold path: chains that overflowed the LDS list (practically never)
    unsigned long long mask = __ballot(resume >= 0);
    while (mask) {
        int l = __ffsll((long long)mask) - 1;
        int e = __shfl(resume, l, 64);
        while (e >= 0) {
            int off = 0, nx = -1, wz = 0, wwd = 0;
            float sa = 0.f;
            if (lane == 0) {
                int4 pr = pair16[e];
                off = pr.x; nx = pr.y; wz = pr.z; wwd = pr.w;
                sa = sacc[e];
            }
            off = __shfl(off, 0, 64);
            wz = __shfl(wz, 0, 64);
            wwd = __shfl(wwd, 0, 64);
            sa = __shfl(sa, 0, 64);
            e = __shfl(nx, 0, 64);
            unsigned wsel = (unsigned)(g ? wwd : wz);
            float2 wf = __half22float2(*(const __half2*)&wsel);
            unsigned short uu = *(const unsigned short*)((const char*)logq + off + lane * 2);
            int q0 = (signed char)(uu & 0xff);
            int q1 = (signed char)(uu >> 8);
            dna += wf.x; dnb += wf.y;
            acc0 = fmaf(wf.x * sa, (float)q0, acc0);
            acc1 = fmaf(wf.y * sa, (float)q1, acc1);
        }
        mask &= mask - 1;
    }

    if (!valid) return;

    // finalize: relu(num/den + bias) -> expmap0 -> proj (post-expmap norm analytic)
    float v0 = acc0 / fmaxf(dna, MIN_NORM) + conv_bias[lane];
    float v1 = acc1 / fmaxf(dnb, MIN_NORM) + conv_bias[lane + 64];
    v0 = fmaxf(v0, 0.f);
    v1 = fmaxf(v1, 0.f);
    float n2 = wave_reduce_sum(v0 * v0 + v1 * v1);
    float nn = fmaxf(sqrtf(n2), MIN_NORM);
    float tv = fast_tanh(nn);
    float s = tv / nn;
    float r0 = s * v0, r1 = s * v1;
    float rn = fmaxf(tv, MIN_NORM);
    if (rn > MAXNORM) { float f = MAXNORM / rn; r0 *= f; r1 *= f; }
    out[(size_t)n * 128 + lane] = r0;
    out[(size_t)n * 128 + 64 + lane] = r1;
}

extern "C" void kernel_launch(void* const* d_in, const int* in_sizes, int n_in,
                              void* d_out, int out_size, void* d_ws, size_t ws_size,
                              hipStream_t stream)
{
    const float* x        = (const float*)d_in[0];
    const float* W        = (const float*)d_in[1];
    const float* lin_bias = (const float*)d_in[2];
    const float* att      = (const float*)d_in[3];
    const float* conv_bias= (const float*)d_in[4];
    const int*   esrc     = (const int*)d_in[5];
    const int*   edst     = (const int*)d_in[6];
    int N = in_sizes[0] / 128;
    int E = in_sizes[5];
    float* out = (float*)d_out;

    char* p = (char*)d_ws;
    float* bbuf   = (float*)p;  p += 256 * 4;
    unsigned short* whi = (unsigned short*)p; p += 16384 * 2;
    unsigned short* wlo = (unsigned short*)p; p += 16384 * 2;
    float* s_i    = (float*)p;  p += (size_t)N * 4 * 4;
    float* s_j    = (float*)p;  p += (size_t)N * 4 * 4;
    float* scl    = (float*)p;  p += (size_t)N * 4;
    int*   head   = (int*)p;    p += (size_t)N * 16 * 4;
    int4*  pair16 = (int4*)p;   p += (size_t)E * 16;
    float* sacc   = (float*)p;  p += (size_t)E * 4;
    unsigned short* logq = (unsigned short*)p; p += (size_t)N * 64 * 2;

    int headN = N * 16;
    int prepBlocks = 65 + (headN / 4 + 255) / 256;
    prep_kernel<<<prepBlocks, 256, 0, stream>>>(W, whi, wlo, lin_bias, bbuf, head, headN);
    int nTiles = (N + 15) / 16;
    node_kernel<<<nTiles, 256, 0, stream>>>(x, whi, wlo, bbuf, att, logq, scl, s_i, s_j, N);
    buildw_kernel<<<(E + 255) / 256, 256, 0, stream>>>(esrc, edst, E, s_i, s_j, scl,
                                                       head, pair16, sacc);
    aggregate_kernel<<<(N + 3) / 4, 256, 0, stream>>>(
        head, pair16, sacc, s_i, s_j, scl, logq, conv_bias, out, N);
}

// Round 14
// 120.117 us; speedup vs baseline: 1.0534x; 1.0534x over previous
//
#include <hip/hip_runtime.h>
#include <hip/hip_fp16.h>
#include <math.h>

#define EPSF 1e-7f
#define MIN_NORM 1e-15f
#define MAXNORM 0.996f   // (1 - 0.004)/sqrt(c), c=1
#define NEG_SLOPE 0.2f

typedef __attribute__((ext_vector_type(8))) short short8;
typedef __attribute__((ext_vector_type(4))) float f32x4;

__device__ __forceinline__ float wave_reduce_sum(float v) {
    #pragma unroll
    for (int m = 1; m < 64; m <<= 1) v += __shfl_xor(v, m, 64);
    return v;
}

// fast tanh via HW exp: t = 1 - 2/(e^{2x}+1). Safe for x>=0 (saturates to 1).
__device__ __forceinline__ float fast_tanh(float x) {
    float e = __expf(2.f * x);
    return 1.f - 2.f / (e + 1.f);
}

// fast artanh via HW log: 0.5*ln((1+x)/(1-x)), input clamped like reference
__device__ __forceinline__ float fast_artanh(float x) {
    x = fminf(fmaxf(x, -1.f + EPSF), 1.f - EPSF);
    return 0.5f * __logf((1.f + x) / (1.f - x));
}

__device__ __forceinline__ float lrelu(float a) {
    return a < 0.f ? a * NEG_SLOPE : a;
}

// bf16 round-to-nearest-even (no NaN handling; inputs are tame)
__device__ __forceinline__ unsigned short f2bf(float f) {
    unsigned u = __float_as_uint(f);
    u += 0x7FFFu + ((u >> 16) & 1u);
    return (unsigned short)(u >> 16);
}
__device__ __forceinline__ float bf2f(unsigned short h) {
    return __uint_as_float(((unsigned)h) << 16);
}

// ---- K0: prep = wsplit (blocks 0..63) + hyp bias (block 64) + head init (65..)
__global__ void prep_kernel(const float* __restrict__ W,
                            unsigned short* __restrict__ whi,
                            unsigned short* __restrict__ wlo,
                            const float* __restrict__ lin_bias,
                            float* __restrict__ bbuf,
                            int* __restrict__ head, int headN) {
    if (blockIdx.x >= 65) {
        int i = (blockIdx.x - 65) * 1024 + threadIdx.x * 4;
        if (i < headN) *(int4*)&head[i] = make_int4(-1, -1, -1, -1);
        return;
    }
    if (blockIdx.x == 64) {
        if (threadIdx.x >= 64) return;
        int lane = threadIdx.x;
        float u0 = lin_bias[lane], u1 = lin_bias[lane + 64];
        float n2 = wave_reduce_sum(u0 * u0 + u1 * u1);
        float n = fmaxf(sqrtf(n2), MIN_NORM);
        float s = tanhf(n) / n;
        float b0 = s * u0, b1 = s * u1;
        float bn = fmaxf(tanhf(n), MIN_NORM);
        float fn2 = bn * bn;
        if (bn > MAXNORM) { float f = MAXNORM / bn; b0 *= f; b1 *= f; fn2 = MAXNORM * MAXNORM; }
        bbuf[lane] = b0;
        bbuf[lane + 64] = b1;
        if (lane == 0) bbuf[128] = fn2;
        return;
    }
    int idx = blockIdx.x * 256 + threadIdx.x;   // 0..16383
    int i = idx & 7, l = (idx >> 3) & 63, ts = idx >> 9;
    int s = ts & 3, t = ts >> 2;
    int o = t * 16 + (l & 15);
    int k = s * 32 + ((l >> 4) * 8) + i;
    float f = W[o * 128 + k];
    unsigned short h = f2bf(f);
    unsigned short lo = f2bf(f - bf2f(h));
    whi[idx] = h;
    wlo[idx] = lo;
}

// ---- K1: per-node transform, MFMA matvec (bf16x3) + 16-lane-per-node chain.
// Fast HW transcendentals. Outputs: log_xb bf16 rows, s_i/s_j permuted [h0,h2,h1,h3].
#define DPAD 132
__global__ __launch_bounds__(256) void node_kernel(
    const float* __restrict__ x,
    const unsigned short* __restrict__ whi, const unsigned short* __restrict__ wlo,
    const float* __restrict__ bbuf, const float* __restrict__ att,
    unsigned short* __restrict__ log_xb,
    float* __restrict__ s_i, float* __restrict__ s_j, int N)
{
    __shared__ float mxs[16][DPAD];
    __shared__ float xn2s[16];
    int tid = threadIdx.x, wave = tid >> 6, lane = tid & 63;
    int nbase = blockIdx.x * 16;
    int arow = lane & 15, kgrp = lane >> 4;
    int anode = min(nbase + arow, N - 1);

    f32x4 acc0 = {0.f, 0.f, 0.f, 0.f};
    f32x4 acc1 = {0.f, 0.f, 0.f, 0.f};
    int t0 = wave * 2, t1 = wave * 2 + 1;
    float x2loc = 0.f;

    #pragma unroll
    for (int s = 0; s < 4; ++s) {
        const float* xp = x + (size_t)anode * 128 + s * 32 + kgrp * 8;
        float4 xa = *(const float4*)xp;
        float4 xb = *(const float4*)(xp + 4);
        float xv[8] = {xa.x, xa.y, xa.z, xa.w, xb.x, xb.y, xb.z, xb.w};
        short8 ahi, alo;
        #pragma unroll
        for (int i = 0; i < 8; ++i) {
            unsigned short h = f2bf(xv[i]);
            unsigned short l = f2bf(xv[i] - bf2f(h));
            ahi[i] = (short)h;
            alo[i] = (short)l;
        }
        if (wave == 0) {
            #pragma unroll
            for (int i = 0; i < 8; ++i) x2loc = fmaf(xv[i], xv[i], x2loc);
        }
        short8 bh0 = *(const short8*)(whi + ((size_t)(t0 * 4 + s) * 64 + lane) * 8);
        short8 bl0 = *(const short8*)(wlo + ((size_t)(t0 * 4 + s) * 64 + lane) * 8);
        short8 bh1 = *(const short8*)(whi + ((size_t)(t1 * 4 + s) * 64 + lane) * 8);
        short8 bl1 = *(const short8*)(wlo + ((size_t)(t1 * 4 + s) * 64 + lane) * 8);
        acc0 = __builtin_amdgcn_mfma_f32_16x16x32_bf16(ahi, bh0, acc0, 0, 0, 0);
        acc0 = __builtin_amdgcn_mfma_f32_16x16x32_bf16(alo, bh0, acc0, 0, 0, 0);
        acc0 = __builtin_amdgcn_mfma_f32_16x16x32_bf16(ahi, bl0, acc0, 0, 0, 0);
        acc1 = __builtin_amdgcn_mfma_f32_16x16x32_bf16(ahi, bh1, acc1, 0, 0, 0);
        acc1 = __builtin_amdgcn_mfma_f32_16x16x32_bf16(alo, bh1, acc1, 0, 0, 0);
        acc1 = __builtin_amdgcn_mfma_f32_16x16x32_bf16(ahi, bl1, acc1, 0, 0, 0);
    }
    if (wave == 0) {
        x2loc += __shfl_xor(x2loc, 16, 64);
        x2loc += __shfl_xor(x2loc, 32, 64);
        if (lane < 16) xn2s[lane] = x2loc;
    }
    #pragma unroll
    for (int r = 0; r < 4; ++r) {
        mxs[kgrp * 4 + r][t0 * 16 + arow] = acc0[r];
        mxs[kgrp * 4 + r][t1 * 16 + arow] = acc1[r];
    }
    __syncthreads();

    // ---- chain: 16 lanes per node, 8 dims per lane, 4 nodes per wave ----
    int g16 = lane >> 4, l16 = lane & 15;
    int nn = wave * 4 + g16;
    int node = nbase + nn;
    bool valid = node < N;
    int head = l16 >> 2;
    int dbase = l16 * 8;
    int dd8 = (l16 & 3) * 8;
    float bb[8], aiv[8], ajv[8];
    #pragma unroll
    for (int j = 0; j < 8; ++j) {
        bb[j] = bbuf[dbase + j];
        aiv[j] = att[head * 64 + dd8 + j];
        ajv[j] = att[head * 64 + 32 + dd8 + j];
    }
    float y2 = bbuf[128];

    float4 va = *(const float4*)&mxs[nn][dbase];
    float4 vb = *(const float4*)&mxs[nn][dbase + 4];
    float v[8] = {va.x, va.y, va.z, va.w, vb.x, vb.y, vb.z, vb.w};

    float mq = 0.f;
    #pragma unroll
    for (int j = 0; j < 8; ++j) mq = fmaf(v[j], v[j], mq);
    #pragma unroll
    for (int m = 1; m < 16; m <<= 1) mq += __shfl_xor(mq, m, 64);

    float xn2 = xn2s[nn];
    float xn = fmaxf(sqrtf(xn2), MIN_NORM);
    float mxn = fmaxf(sqrtf(mq), MIN_NORM);
    float t = fast_tanh(mxn / xn * fast_artanh(xn));
    float scl = t / mxn;
    bool zero = (mq == 0.f);
    float r[8];
    #pragma unroll
    for (int j = 0; j < 8; ++j) r[j] = zero ? 0.f : scl * v[j];
    float rn2 = zero ? 0.f : t * t;
    float rn = zero ? MIN_NORM : fmaxf(fabsf(t), MIN_NORM);
    float x2 = rn2;
    if (rn > MAXNORM) {
        float f = MAXNORM / rn;
        #pragma unroll
        for (int j = 0; j < 8; ++j) r[j] *= f;
        x2 = MAXNORM * MAXNORM;
    }
    float xy = 0.f;
    #pragma unroll
    for (int j = 0; j < 8; ++j) xy = fmaf(r[j], bb[j], xy);
    #pragma unroll
    for (int m = 1; m < 16; m <<= 1) xy += __shfl_xor(xy, m, 64);
    float cA = 1.f + 2.f * xy + y2;
    float cB = 1.f - x2;
    float dn = fmaxf(1.f + 2.f * xy + x2 * y2, MIN_NORM);
    float inv = 1.f / dn;
    float h[8];
    #pragma unroll
    for (int j = 0; j < 8; ++j) h[j] = (cA * r[j] + cB * bb[j]) * inv;
    float hq = 0.f;
    #pragma unroll
    for (int j = 0; j < 8; ++j) hq = fmaf(h[j], h[j], hq);
    #pragma unroll
    for (int m = 1; m < 16; m <<= 1) hq += __shfl_xor(hq, m, 64);
    float hn = fmaxf(sqrtf(hq), MIN_NORM);
    float ln2 = hq;
    if (hn > MAXNORM) {
        float f = MAXNORM / hn;
        #pragma unroll
        for (int j = 0; j < 8; ++j) h[j] *= f;
        ln2 = MAXNORM * MAXNORM;
    }
    float lnn = fmaxf(sqrtf(ln2), MIN_NORM);
    float ls = fast_artanh(lnn) / lnn;
    float lv[8];
    #pragma unroll
    for (int j = 0; j < 8; ++j) lv[j] = ls * h[j];

    if (valid) {
        uint4 pk;
        pk.x = (unsigned)f2bf(lv[0]) | ((unsigned)f2bf(lv[1]) << 16);
        pk.y = (unsigned)f2bf(lv[2]) | ((unsigned)f2bf(lv[3]) << 16);
        pk.z = (unsigned)f2bf(lv[4]) | ((unsigned)f2bf(lv[5]) << 16);
        pk.w = (unsigned)f2bf(lv[6]) | ((unsigned)f2bf(lv[7]) << 16);
        *(uint4*)&log_xb[(size_t)node * 128 + dbase] = pk;
    }
    float pi = 0.f, pj = 0.f;
    #pragma unroll
    for (int j = 0; j < 8; ++j) {
        pi = fmaf(lv[j], aiv[j], pi);
        pj = fmaf(lv[j], ajv[j], pj);
    }
    pi += __shfl_xor(pi, 1, 64); pi += __shfl_xor(pi, 2, 64);
    pj += __shfl_xor(pj, 1, 64); pj += __shfl_xor(pj, 2, 64);
    if (valid && (l16 & 3) == 0) {
        int pos = ((head & 1) << 1) | (head >> 1);   // [h0,h2,h1,h3] order
        s_i[(size_t)node * 4 + pos] = pi;
        s_j[(size_t)node * 4 + pos] = pj;
    }
}

// ---- K2: fused list-build + streaming weight precompute (R8-proven).
// pair16[e] = { src_byte_offset, next, half2(w_h0,w_h2), half2(w_h1,w_h3) }
__global__ void buildw_kernel(const int* __restrict__ src, const int* __restrict__ dst,
                              int E, const float* __restrict__ s_i,
                              const float* __restrict__ s_j,
                              int* __restrict__ head, int4* __restrict__ pair16)
{
    int e = blockIdx.x * blockDim.x + threadIdx.x;
    if (e >= E) return;
    int s_ = src[e], d_ = dst[e];
    int prev = atomicExch(&head[(size_t)d_ * 16 + (e & 15)], e);
    float4 si = *(const float4*)(s_i + (size_t)d_ * 4);
    float4 sj = *(const float4*)(s_j + (size_t)s_ * 4);
    float w0 = __expf(lrelu(si.x + sj.x));
    float w1 = __expf(lrelu(si.y + sj.y));
    float w2 = __expf(lrelu(si.z + sj.z));
    float w3 = __expf(lrelu(si.w + sj.w));
    __half2 h01 = __floats2half2_rn(w0, w1);   // (h0, h2) in permuted order
    __half2 h23 = __floats2half2_rn(w2, w3);   // (h1, h3)
    int4 pr;
    pr.x = s_ << 8;        // byte offset of message row (256 B/row)
    pr.y = prev;
    pr.z = *(int*)&h01;
    pr.w = *(int*)&h23;
    pair16[e] = pr;
}

// ---- K3: aggregate. Walk 16 chains -> LDS {off, w-words}; 8-unrolled hot loop
// (16 message gathers in flight).
#define MAXS 128
__global__ __launch_bounds__(256) void aggregate_kernel(
    const int* __restrict__ head, const int4* __restrict__ pair16,
    const float* __restrict__ s_i, const float* __restrict__ s_j,
    const unsigned short* __restrict__ log_xb, const float* __restrict__ conv_bias,
    float* __restrict__ out, int N)
{
    __shared__ __align__(16) int slist[4][MAXS];
    __shared__ __align__(16) unsigned wlist[4][MAXS * 2];
    __shared__ int scnt[4];
    int tid = threadIdx.x, wave = tid >> 6, lane = tid & 63;
    int n = blockIdx.x * 4 + wave;
    bool valid = n < N;

    if (lane == 0) scnt[wave] = 0;
    __syncthreads();

    int resume = -1;
    if (valid && lane < 16) {
        int e = head[(size_t)n * 16 + lane];
        while (e >= 0) {
            int4 pr = pair16[e];
            int pos = atomicAdd(&scnt[wave], 1);
            if (pos < MAXS) {
                slist[wave][pos] = pr.x;
                wlist[wave][pos * 2]     = (unsigned)pr.z;
                wlist[wave][pos * 2 + 1] = (unsigned)pr.w;
                e = pr.y;
            } else { resume = e; break; }
        }
    }
    __syncthreads();

    int g = lane >> 5;
    float acc0 = 0.f, acc1 = 0.f, dna = 0.f, dnb = 0.f;

    int deg = 0;
    if (valid) {
        deg = min(scnt[wave], MAXS);
        float2 si2  = *(const float2*)(s_i + (size_t)n * 4 + g * 2);
        float2 sj2n = *(const float2*)(s_j + (size_t)n * 4 + g * 2);
        float ea = __expf(lrelu(si2.x + sj2n.x));
        float eb = __expf(lrelu(si2.y + sj2n.y));
        dna = ea; dnb = eb;
        const unsigned short* mrow = log_xb + (size_t)n * 128;
        acc0 = ea * bf2f(mrow[lane]);
        acc1 = eb * bf2f(mrow[lane + 64]);

        const int* sl = slist[wave];
        const unsigned* wlv = wlist[wave];
        int i = 0;
        for (; i + 8 <= deg; i += 8) {
            int4 offqa = *(const int4*)&sl[i];
            int4 offqb = *(const int4*)&sl[i + 4];
            int offs[8] = {offqa.x, offqa.y, offqa.z, offqa.w,
                           offqb.x, offqb.y, offqb.z, offqb.w};
            unsigned ww[8];
            unsigned short ma[8], mb[8];
            #pragma unroll
            for (int j = 0; j < 8; ++j) {
                ww[j] = wlv[(i + j) * 2 + g];
                const unsigned short* mr =
                    (const unsigned short*)((const char*)log_xb + offs[j]);
                ma[j] = mr[lane];
                mb[j] = mr[lane + 64];
            }
            #pragma unroll
            for (int j = 0; j < 8; ++j) {
                float2 wf = __half22float2(*(const __half2*)&ww[j]);
                dna += wf.x; dnb += wf.y;
                acc0 = fmaf(wf.x, bf2f(ma[j]), acc0);
                acc1 = fmaf(wf.y, bf2f(mb[j]), acc1);
            }
        }
        for (; i + 4 <= deg; i += 4) {
            int4 offq = *(const int4*)&sl[i];
            int offs[4] = {offq.x, offq.y, offq.z, offq.w};
            unsigned ww[4];
            unsigned short ma[4], mb[4];
            #pragma unroll
            for (int j = 0; j < 4; ++j) {
                ww[j] = wlv[(i + j) * 2 + g];
                const unsigned short* mr =
                    (const unsigned short*)((const char*)log_xb + offs[j]);
                ma[j] = mr[lane];
                mb[j] = mr[lane + 64];
            }
            #pragma unroll
            for (int j = 0; j < 4; ++j) {
                float2 wf = __half22float2(*(const __half2*)&ww[j]);
                dna += wf.x; dnb += wf.y;
                acc0 = fmaf(wf.x, bf2f(ma[j]), acc0);
                acc1 = fmaf(wf.y, bf2f(mb[j]), acc1);
            }
        }
        for (; i < deg; ++i) {
            unsigned w = wlv[i * 2 + g];
            const unsigned short* mr =
                (const unsigned short*)((const char*)log_xb + sl[i]);
            float2 wf = __half22float2(*(const __half2*)&w);
            dna += wf.x; dnb += wf.y;
            acc0 = fmaf(wf.x, bf2f(mr[lane]), acc0);
            acc1 = fmaf(wf.y, bf2f(mr[lane + 64]), acc1);
        }
    }

    // cold path: chains that overflowed the LDS list (practically never)
    unsigned long long mask = __ballot(resume >= 0);
    while (mask) {
        int l = __ffsll((long long)mask) - 1;
        int e = __shfl(resume, l, 64);
        while (e >= 0) {
            int off = 0, nx = -1, wz = 0, wwd = 0;
            if (lane == 0) { int4 pr = pair16[e]; off = pr.x; nx = pr.y; wz = pr.z; wwd = pr.w; }
            off = __shfl(off, 0, 64);
            wz = __shfl(wz, 0, 64);
            wwd = __shfl(wwd, 0, 64);
            e = __shfl(nx, 0, 64);
            unsigned wsel = (unsigned)(g ? wwd : wz);
            float2 wf = __half22float2(*(const __half2*)&wsel);
            const unsigned short* mr = (const unsigned short*)((const char*)log_xb + off);
            dna += wf.x; dnb += wf.y;
            acc0 = fmaf(wf.x, bf2f(mr[lane]), acc0);
            acc1 = fmaf(wf.y, bf2f(mr[lane + 64]), acc1);
        }
        mask &= mask - 1;
    }

    if (!valid) return;

    // finalize: relu(num/den + bias) -> expmap0 -> proj (post-expmap norm analytic)
    float v0 = acc0 / fmaxf(dna, MIN_NORM) + conv_bias[lane];
    float v1 = acc1 / fmaxf(dnb, MIN_NORM) + conv_bias[lane + 64];
    v0 = fmaxf(v0, 0.f);
    v1 = fmaxf(v1, 0.f);
    float n2 = wave_reduce_sum(v0 * v0 + v1 * v1);
    float nn = fmaxf(sqrtf(n2), MIN_NORM);
    float tv = fast_tanh(nn);
    float s = tv / nn;
    float r0 = s * v0, r1 = s * v1;
    float rn = fmaxf(tv, MIN_NORM);
    if (rn > MAXNORM) { float f = MAXNORM / rn; r0 *= f; r1 *= f; }
    out[(size_t)n * 128 + lane] = r0;
    out[(size_t)n * 128 + 64 + lane] = r1;
}

extern "C" void kernel_launch(void* const* d_in, const int* in_sizes, int n_in,
                              void* d_out, int out_size, void* d_ws, size_t ws_size,
                              hipStream_t stream)
{
    const float* x        = (const float*)d_in[0];
    const float* W        = (const float*)d_in[1];
    const float* lin_bias = (const float*)d_in[2];
    const float* att      = (const float*)d_in[3];
    const float* conv_bias= (const float*)d_in[4];
    const int*   esrc     = (const int*)d_in[5];
    const int*   edst     = (const int*)d_in[6];
    int N = in_sizes[0] / 128;
    int E = in_sizes[5];
    float* out = (float*)d_out;

    char* p = (char*)d_ws;
    float* bbuf   = (float*)p;  p += 256 * 4;
    unsigned short* whi = (unsigned short*)p; p += 16384 * 2;
    unsigned short* wlo = (unsigned short*)p; p += 16384 * 2;
    float* s_i    = (float*)p;  p += (size_t)N * 4 * 4;
    float* s_j    = (float*)p;  p += (size_t)N * 4 * 4;
    int*   head   = (int*)p;    p += (size_t)N * 16 * 4;
    int4*  pair16 = (int4*)p;   p += (size_t)E * 16;
    unsigned short* log_xb = (unsigned short*)p; p += (size_t)N * 128 * 2;

    int headN = N * 16;
    int prepBlocks = 65 + (headN / 4 + 255) / 256;
    prep_kernel<<<prepBlocks, 256, 0, stream>>>(W, whi, wlo, lin_bias, bbuf, head, headN);
    int nTiles = (N + 15) / 16;
    node_kernel<<<nTiles, 256, 0, stream>>>(x, whi, wlo, bbuf, att, log_xb, s_i, s_j, N);
    buildw_kernel<<<(E + 255) / 256, 256, 0, stream>>>(esrc, edst, E, s_i, s_j, head, pair16);
    aggregate_kernel<<<(N + 3) / 4, 256, 0, stream>>>(
        head, pair16, s_i, s_j, log_xb, conv_bias, out, N);
}